// Round 5
// baseline (132.355 us; speedup 1.0000x reference)
//
#include <hip/hip_runtime.h>

// BottleneckAdapter: out = residual + Wup·( swish(Wl1·n+bl1) * (Wl2·n+bl2) ),
// n = LN( (Wdown·Wproj)·x ).  W_comb = Wdown@Wproj precomputed per-launch.
//
// Dims: B=16 S=2048 C=768 Q=1024 D=64 -> ROWS=32768.
// R5: k_up -> persistent 1-block/CU pipeline (T3/T4):
//     - wupf fragments preloaded to VGPRs once (no reloads in loop)
//     - per tile: prefetch(t+1) {2 ag loads + 8 res global_load_lds DMAs},
//       s_waitcnt vmcnt(18) (counted, never 0), 16 MFMA, swizzled ds_read,
//       add, plain store. DMA latency hidden under a full tile period.
//     - res LDS double-buffer 2x8x16x128 f32 = 128 KiB, wave-private slices,
//       no barriers; XOR slot^(row&7) swizzle applied on DMA SOURCE.

#define CDIM 768
#define QDIM 1024

typedef __attribute__((ext_vector_type(8))) short bf16x8;
typedef __attribute__((ext_vector_type(4))) float f32x4;

__device__ __forceinline__ ushort f2bf(float f) {
  union { float f; unsigned u; } v; v.f = f;
  unsigned r = v.u + 0x7fffu + ((v.u >> 16) & 1u);   // RNE
  return (ushort)(r >> 16);
}

__device__ __forceinline__ void gload16(const float* g, float* lds) {
  __builtin_amdgcn_global_load_lds(
      (const __attribute__((address_space(1))) void*)g,
      (__attribute__((address_space(3))) void*)lds, 16, 0, 0);
}

// ---- K1: partial W_comb[d][c] = sum_q Wdown[d][q]*Wproj[q][c], split in 8 q-chunks.
// part[qc][c][d]  (8 x 768 x 64 f32)
__global__ void k_wcomb(const float* __restrict__ Wproj, const float* __restrict__ Wdown,
                        float* __restrict__ part) {
  int bid = blockIdx.x;                 // 768 blocks = 12 cb * 8 db * 8 qc
  int cb = bid % 12, db = (bid / 12) % 8, qc = bid / 96;
  int l = threadIdx.x;                  // 64
  int c = cb * 64 + l;
  float acc[8];
  #pragma unroll
  for (int i = 0; i < 8; ++i) acc[i] = 0.f;
  int q0 = qc * 128;
  for (int q = q0; q < q0 + 128; ++q) {
    float xp = Wproj[q * CDIM + c];     // coalesced across lanes
    #pragma unroll
    for (int i = 0; i < 8; ++i)
      acc[i] = fmaf(Wdown[(db * 8 + i) * QDIM + q], xp, acc[i]);  // uniform, L2
  }
  #pragma unroll
  for (int i = 0; i < 8; ++i)
    part[((size_t)qc * CDIM + c) * 64 + db * 8 + i] = acc[i];
}

// ---- K2: sum partials + arrange all weights into MFMA fragment order (bf16).
// Fragment convention (k-permutation trick; cancels between the two operands):
// element (lane l, j) of tile (ks,nf) = M[16*nf+(l&15)][32*ks + 8*(l>>4)+j]
__global__ void k_arrange(const float* __restrict__ part, const float* __restrict__ Wup,
                          const float* __restrict__ Wl1, const float* __restrict__ Wl2,
                          ushort* __restrict__ wcf, ushort* __restrict__ wupf,
                          ushort* __restrict__ wl1f, ushort* __restrict__ wl2f) {
  int idx = blockIdx.x * 256 + threadIdx.x;      // 480*256 = 122880 exactly
  if (idx < 49152) {                             // wcf: flat = ((ks*4+nf)*64+l)*8+j, ks<24
    int i0 = idx;
    int j = i0 & 7, l = (i0 >> 3) & 63, t = i0 >> 9;
    int g = l >> 4, r16 = l & 15;
    int nf = t & 3, ks = t >> 2;
    int k = 32 * ks + 8 * g + j, n = 16 * nf + r16;   // k=c-index, n=d-index
    float s = 0.f;
    #pragma unroll
    for (int qc = 0; qc < 8; ++qc) s += part[((size_t)qc * CDIM + k) * 64 + n];
    wcf[i0] = f2bf(s);
  } else if (idx < 49152 + 65536) {              // wupf: flat = ((nf*2+ks)*64+l)*8+j, nf<64
    int i2 = idx - 49152;
    int j = i2 & 7, l = (i2 >> 3) & 63, t = i2 >> 9;
    int g = l >> 4, r16 = l & 15;
    int ks = t & 1, nf = t >> 1;
    int k = 32 * ks + 8 * g + j, n = 16 * nf + r16;   // Wup row n, k-col
    wupf[i2] = f2bf(Wup[n * 64 + k]);
  } else if (idx < 49152 + 65536 + 4096) {       // wl1f: flat = ((ks*4+nf)*64+l)*8+j
    int i3 = idx - (49152 + 65536);
    int j = i3 & 7, l = (i3 >> 3) & 63, t = i3 >> 9;
    int g = l >> 4, r16 = l & 15;
    int nf = t & 3, ks = t >> 2;
    int k = 32 * ks + 8 * g + j, e = 16 * nf + r16;   // o1[e] = sum_k n[k]*Wl1[e][k]
    wl1f[i3] = f2bf(Wl1[e * 64 + k]);
  } else {                                       // wl2f
    int i4 = idx - (49152 + 65536 + 4096);
    int j = i4 & 7, l = (i4 >> 3) & 63, t = i4 >> 9;
    int g = l >> 4, r16 = l & 15;
    int nf = t & 3, ks = t >> 2;
    int k = 32 * ks + 8 * g + j, e = 16 * nf + r16;
    wl2f[i4] = f2bf(Wl2[e * 64 + k]);
  }
}

// ---- K_A: x -> down-proj -> LN -> SwiGLU -> a[] (bf16). 16 rows/WG, 4 waves.
__global__ __launch_bounds__(256, 6)
void k_act(const float* __restrict__ xg,
           const float* __restrict__ gamma, const float* __restrict__ beta,
           const float* __restrict__ bl1, const float* __restrict__ bl2,
           const ushort* __restrict__ wcf,
           const ushort* __restrict__ wl1f, const ushort* __restrict__ wl2f,
           ushort* __restrict__ ag) {
  __shared__ ushort smem[12416];
  ushort (*x_lds)[776] = reinterpret_cast<ushort(*)[776]>(smem);
  float  (*d_lds)[68]  = reinterpret_cast<float (*)[68]>(smem);
  ushort (*n_lds)[72]  = reinterpret_cast<ushort(*)[72]>(reinterpret_cast<char*>(smem) + 4608);

  const int tid = threadIdx.x;
  const int w = tid >> 6, l = tid & 63, g = l >> 4, r16 = l & 15;
  const int row0 = blockIdx.x * 16;

  // Phase A: stage x (16x768 f32) -> LDS bf16, float4-vectorized, coalesced.
  #pragma unroll
  for (int i = 0; i < 12; ++i) {
    int f4 = i * 256 + tid;                    // 0..3071
    int r = f4 / 192;                          // 768/4=192 float4 per row
    int c4 = (f4 - r * 192) * 4;
    const float4 v = *reinterpret_cast<const float4*>(xg + (size_t)(row0 + r) * CDIM + c4);
    ushort4 b;
    b.x = f2bf(v.x); b.y = f2bf(v.y); b.z = f2bf(v.z); b.w = f2bf(v.w);
    *reinterpret_cast<ushort4*>(&x_lds[r][c4]) = b;
  }
  __syncthreads();

  // Phase B: d(16x64) = x(16x768) * Wcomb^T. Wave w owns n-frag w.
  f32x4 dacc = {0.f, 0.f, 0.f, 0.f};
  #pragma unroll 8
  for (int ks = 0; ks < 24; ++ks) {
    bf16x8 a = *reinterpret_cast<const bf16x8*>(&x_lds[r16][ks * 32 + 8 * g]);
    bf16x8 b = *reinterpret_cast<const bf16x8*>(wcf + ((size_t)(ks * 4 + w) * 64 + l) * 8);
    dacc = __builtin_amdgcn_mfma_f32_16x16x32_bf16(a, b, dacc, 0, 0, 0);
  }
  __syncthreads();                             // all x reads done before d overwrite
  #pragma unroll
  for (int rg = 0; rg < 4; ++rg) d_lds[4 * g + rg][16 * w + r16] = dacc[rg];
  __syncthreads();

  // Phase C: LayerNorm over D=64.
  {
    int row = 4 * w + g;
    f32x4 v = *reinterpret_cast<const f32x4*>(&d_lds[row][4 * r16]);
    float s  = v[0] + v[1] + v[2] + v[3];
    float sq = v[0]*v[0] + v[1]*v[1] + v[2]*v[2] + v[3]*v[3];
    #pragma unroll
    for (int m = 1; m < 16; m <<= 1) {
      s  += __shfl_xor(s, m, 64);
      sq += __shfl_xor(sq, m, 64);
    }
    float mu  = s * (1.f / 64.f);
    float var = sq * (1.f / 64.f) - mu * mu;
    float rs  = rsqrtf(var + 1e-5f);
    const float4 gm = *reinterpret_cast<const float4*>(gamma + 4 * r16);
    const float4 bt = *reinterpret_cast<const float4*>(beta  + 4 * r16);
    ushort4 nb;
    nb.x = f2bf((v[0] - mu) * rs * gm.x + bt.x);
    nb.y = f2bf((v[1] - mu) * rs * gm.y + bt.y);
    nb.z = f2bf((v[2] - mu) * rs * gm.z + bt.z);
    nb.w = f2bf((v[3] - mu) * rs * gm.w + bt.w);
    *reinterpret_cast<ushort4*>(&n_lds[row][4 * r16]) = nb;
  }
  __syncthreads();

  // Phase D: o1/o2 (16x64, K=64) + bias + swish*gate -> global a[] (bf16).
  {
    bf16x8 a0 = *reinterpret_cast<const bf16x8*>(&n_lds[r16][8 * g]);
    bf16x8 a1 = *reinterpret_cast<const bf16x8*>(&n_lds[r16][32 + 8 * g]);
    bf16x8 b10 = *reinterpret_cast<const bf16x8*>(wl1f + ((size_t)(0 * 4 + w) * 64 + l) * 8);
    bf16x8 b11 = *reinterpret_cast<const bf16x8*>(wl1f + ((size_t)(1 * 4 + w) * 64 + l) * 8);
    bf16x8 b20 = *reinterpret_cast<const bf16x8*>(wl2f + ((size_t)(0 * 4 + w) * 64 + l) * 8);
    bf16x8 b21 = *reinterpret_cast<const bf16x8*>(wl2f + ((size_t)(1 * 4 + w) * 64 + l) * 8);
    f32x4 z = {0.f, 0.f, 0.f, 0.f};
    f32x4 acc1 = __builtin_amdgcn_mfma_f32_16x16x32_bf16(a0, b10, z, 0, 0, 0);
    acc1 = __builtin_amdgcn_mfma_f32_16x16x32_bf16(a1, b11, acc1, 0, 0, 0);
    f32x4 acc2 = __builtin_amdgcn_mfma_f32_16x16x32_bf16(a0, b20, z, 0, 0, 0);
    acc2 = __builtin_amdgcn_mfma_f32_16x16x32_bf16(a1, b21, acc2, 0, 0, 0);
    float bv1 = bl1[16 * w + r16];
    float bv2 = bl2[16 * w + r16];
    #pragma unroll
    for (int rg = 0; rg < 4; ++rg) {
      float o1 = acc1[rg] + bv1;
      float o2 = acc2[rg] + bv2;
      float sw = o1 / (1.f + __expf(-o1));       // o1*sigmoid(o1)
      ag[(size_t)(row0 + 4 * g + rg) * 64 + 16 * w + r16] = f2bf(sw * o2);
    }
  }
}

// ---- K_B: out = res + a * Wup^T.  Persistent pipelined streaming kernel.
// 256 blocks x 512 thr (8 waves, 1 block/CU). Block owns 128 rows = 8 tiles
// of 16 rows x 1024 cols. Wave w owns cols 128w..128w+127 (nf = 8w+nfl).
// Lane l: out-row = l&15, out-cols 128w+16nfl+4*(l>>4)+{0..3}.
__global__ __launch_bounds__(512, 1)
void k_up(const ushort* __restrict__ ag, const float* __restrict__ resg,
          const ushort* __restrict__ wupf, float* __restrict__ outg) {
  __shared__ float res_lds[2][8][16][128];   // 128 KiB, wave-private slices
  const int tid = threadIdx.x;
  const int w = tid >> 6, l = tid & 63, g = l >> 4, r16 = l & 15;
  const int blk_row0 = blockIdx.x * 128;

  // Persistent wupf fragments (64 VGPR), loaded once.
  bf16x8 wf[16];
  #pragma unroll
  for (int nfl = 0; nfl < 8; ++nfl) {
    size_t nf = 8 * w + nfl;
    wf[2 * nfl + 0] = *reinterpret_cast<const bf16x8*>(wupf + ((nf * 2 + 0) * 64 + l) * 8);
    wf[2 * nfl + 1] = *reinterpret_cast<const bf16x8*>(wupf + ((nf * 2 + 1) * 64 + l) * 8);
  }

  bf16x8 af0[2], af1[2];   // ag double-buffer (static-indexed after unroll)

  // Prologue: prefetch tile 0 (ag first, then 8 res DMAs) into buf 0.
  {
    const int trow0 = blk_row0;
    af0[0] = *reinterpret_cast<const bf16x8*>(ag + (size_t)(trow0 + r16) * 64 + 8 * g);
    af1[0] = *reinterpret_cast<const bf16x8*>(ag + (size_t)(trow0 + r16) * 64 + 32 + 8 * g);
    float* base = &res_lds[0][w][0][0];
    #pragma unroll
    for (int i = 0; i < 8; ++i) {
      const int r = 2 * i + (l >> 5);
      const int sp = (l & 31) ^ (r & 7);     // source-side XOR swizzle
      gload16(resg + (size_t)(trow0 + r) * QDIM + 128 * w + 4 * sp, base + i * 256);
    }
  }

  #pragma unroll
  for (int t = 0; t < 8; ++t) {
    const int nt = (t + 1) & 7;              // wrap: t=7 redundantly re-prefetches
    const int nb = (t + 1) & 1;              //       tile 0 (keeps vmcnt uniform)
    const int cb = t & 1;

    // Prefetch tile t+1: 2 ag loads + 8 res DMAs (10 vm ops).
    __builtin_amdgcn_sched_barrier(0);
    {
      const int trow0 = blk_row0 + nt * 16;
      af0[nb] = *reinterpret_cast<const bf16x8*>(ag + (size_t)(trow0 + r16) * 64 + 8 * g);
      af1[nb] = *reinterpret_cast<const bf16x8*>(ag + (size_t)(trow0 + r16) * 64 + 32 + 8 * g);
      float* base = &res_lds[nb][w][0][0];
      #pragma unroll
      for (int i = 0; i < 8; ++i) {
        const int r = 2 * i + (l >> 5);
        const int sp = (l & 31) ^ (r & 7);
        gload16(resg + (size_t)(trow0 + r) * QDIM + 128 * w + 4 * sp, base + i * 256);
      }
    }
    __builtin_amdgcn_sched_barrier(0);
    // Counted wait: 18 = 8 stores(t-1) + 10 prefetch(t+1) may stay in flight;
    // in-order retirement => prefetch(t) (DMAs + ag) complete. Never vmcnt(0).
    if (t == 0) { asm volatile("s_waitcnt vmcnt(10)" ::: "memory"); }
    else        { asm volatile("s_waitcnt vmcnt(18)" ::: "memory"); }
    __builtin_amdgcn_sched_barrier(0);

    const int trow0 = blk_row0 + t * 16;
    f32x4 acc[8];
    #pragma unroll
    for (int nfl = 0; nfl < 8; ++nfl) {
      f32x4 z = {0.f, 0.f, 0.f, 0.f};
      z = __builtin_amdgcn_mfma_f32_16x16x32_bf16(wf[2 * nfl + 0], af0[cb], z, 0, 0, 0);
      acc[nfl] = __builtin_amdgcn_mfma_f32_16x16x32_bf16(wf[2 * nfl + 1], af1[cb], z, 0, 0, 0);
    }
    #pragma unroll
    for (int nfl = 0; nfl < 8; ++nfl) {
      const int sp = (4 * nfl + g) ^ (r16 & 7);   // undo source swizzle
      const f32x4 rv = *reinterpret_cast<const f32x4*>(&res_lds[cb][w][r16][4 * sp]);
      f32x4 o = rv + acc[nfl];
      *reinterpret_cast<f32x4*>(
          outg + (size_t)(trow0 + r16) * QDIM + 128 * w + 16 * nfl + 4 * g) = o;
    }
  }
}

extern "C" void kernel_launch(void* const* d_in, const int* in_sizes, int n_in,
                              void* d_out, int out_size, void* d_ws, size_t ws_size,
                              hipStream_t stream) {
  (void)in_sizes; (void)n_in; (void)out_size; (void)ws_size;
  const float* x     = (const float*)d_in[0];
  const float* resid = (const float*)d_in[1];
  const float* Wproj = (const float*)d_in[2];
  const float* Wdown = (const float*)d_in[3];
  const float* gamma = (const float*)d_in[4];
  const float* beta  = (const float*)d_in[5];
  const float* Wl1   = (const float*)d_in[6];
  const float* bl1   = (const float*)d_in[7];
  const float* Wl2   = (const float*)d_in[8];
  const float* bl2   = (const float*)d_in[9];
  const float* Wup   = (const float*)d_in[10];
  float* out = (float*)d_out;

  char* ws = (char*)d_ws;
  float*  part = (float*)(ws);                   // 8*768*64*4 = 1,572,864 B
  ushort* wcf  = (ushort*)(ws + 1572864);        // 49152*2 =  98,304 B
  ushort* wupf = (ushort*)(ws + 1671168);        // 65536*2 = 131,072 B
  ushort* wl1f = (ushort*)(ws + 1802240);        //  4096*2 =   8,192 B
  ushort* wl2f = (ushort*)(ws + 1810432);        //  4096*2 =   8,192 B
  ushort* ag   = (ushort*)(ws + 1818624);        // 32768*64*2 = 4,194,304 B (end ~6.0MB)

  k_wcomb  <<<768, 64, 0, stream>>>(Wproj, Wdown, part);
  k_arrange<<<480, 256, 0, stream>>>(part, Wup, Wl1, Wl2, wcf, wupf, wl1f, wl2f);
  k_act    <<<2048, 256, 0, stream>>>(x, gamma, beta, bl1, bl2, wcf, wl1f, wl2f, ag);
  k_up     <<<256, 512, 0, stream>>>(ag, resid, wupf, out);
}

// Round 6
// 127.312 us; speedup vs baseline: 1.0396x; 1.0396x over previous
//
#include <hip/hip_runtime.h>

// BottleneckAdapter: out = residual + Wup·( swish(Wl1·n+bl1) * (Wl2·n+bl2) ),
// n = LN( (Wdown·Wproj)·x ).  W_comb = Wdown@Wproj precomputed per-launch.
//
// Dims: B=16 S=2048 C=768 Q=1024 D=64 -> ROWS=32768.
// R6: k_up -> register-streamed res: all 16 res float4 loads issued upfront
//     per lane (16KB in flight per wave, ~190KB/CU at 12 waves/CU), wupf
//     (L2-resident) loads in-loop after them. No DMA, no vmcnt asm, no LDS
//     for res. launch_bounds(256,3) caps VGPR at 168 (no spill headroom risk).

#define CDIM 768
#define QDIM 1024

typedef __attribute__((ext_vector_type(8))) short bf16x8;
typedef __attribute__((ext_vector_type(4))) float f32x4;

__device__ __forceinline__ ushort f2bf(float f) {
  union { float f; unsigned u; } v; v.f = f;
  unsigned r = v.u + 0x7fffu + ((v.u >> 16) & 1u);   // RNE
  return (ushort)(r >> 16);
}

// ---- K1: partial W_comb[d][c] = sum_q Wdown[d][q]*Wproj[q][c], split in 8 q-chunks.
// part[qc][c][d]  (8 x 768 x 64 f32)
__global__ void k_wcomb(const float* __restrict__ Wproj, const float* __restrict__ Wdown,
                        float* __restrict__ part) {
  int bid = blockIdx.x;                 // 768 blocks = 12 cb * 8 db * 8 qc
  int cb = bid % 12, db = (bid / 12) % 8, qc = bid / 96;
  int l = threadIdx.x;                  // 64
  int c = cb * 64 + l;
  float acc[8];
  #pragma unroll
  for (int i = 0; i < 8; ++i) acc[i] = 0.f;
  int q0 = qc * 128;
  for (int q = q0; q < q0 + 128; ++q) {
    float xp = Wproj[q * CDIM + c];     // coalesced across lanes
    #pragma unroll
    for (int i = 0; i < 8; ++i)
      acc[i] = fmaf(Wdown[(db * 8 + i) * QDIM + q], xp, acc[i]);  // uniform, L2
  }
  #pragma unroll
  for (int i = 0; i < 8; ++i)
    part[((size_t)qc * CDIM + c) * 64 + db * 8 + i] = acc[i];
}

// ---- K2: sum partials + arrange all weights into MFMA fragment order (bf16).
// Fragment convention (k-permutation trick; cancels between the two operands):
// element (lane l, j) of tile (ks,nf) = M[16*nf+(l&15)][32*ks + 8*(l>>4)+j]
__global__ void k_arrange(const float* __restrict__ part, const float* __restrict__ Wup,
                          const float* __restrict__ Wl1, const float* __restrict__ Wl2,
                          ushort* __restrict__ wcf, ushort* __restrict__ wupf,
                          ushort* __restrict__ wl1f, ushort* __restrict__ wl2f) {
  int idx = blockIdx.x * 256 + threadIdx.x;      // 480*256 = 122880 exactly
  if (idx < 49152) {                             // wcf: flat = ((ks*4+nf)*64+l)*8+j, ks<24
    int i0 = idx;
    int j = i0 & 7, l = (i0 >> 3) & 63, t = i0 >> 9;
    int g = l >> 4, r16 = l & 15;
    int nf = t & 3, ks = t >> 2;
    int k = 32 * ks + 8 * g + j, n = 16 * nf + r16;   // k=c-index, n=d-index
    float s = 0.f;
    #pragma unroll
    for (int qc = 0; qc < 8; ++qc) s += part[((size_t)qc * CDIM + k) * 64 + n];
    wcf[i0] = f2bf(s);
  } else if (idx < 49152 + 65536) {              // wupf: flat = ((nf*2+ks)*64+l)*8+j, nf<64
    int i2 = idx - 49152;
    int j = i2 & 7, l = (i2 >> 3) & 63, t = i2 >> 9;
    int g = l >> 4, r16 = l & 15;
    int ks = t & 1, nf = t >> 1;
    int k = 32 * ks + 8 * g + j, n = 16 * nf + r16;   // Wup row n, k-col
    wupf[i2] = f2bf(Wup[n * 64 + k]);
  } else if (idx < 49152 + 65536 + 4096) {       // wl1f: flat = ((ks*4+nf)*64+l)*8+j
    int i3 = idx - (49152 + 65536);
    int j = i3 & 7, l = (i3 >> 3) & 63, t = i3 >> 9;
    int g = l >> 4, r16 = l & 15;
    int nf = t & 3, ks = t >> 2;
    int k = 32 * ks + 8 * g + j, e = 16 * nf + r16;   // o1[e] = sum_k n[k]*Wl1[e][k]
    wl1f[i3] = f2bf(Wl1[e * 64 + k]);
  } else {                                       // wl2f
    int i4 = idx - (49152 + 65536 + 4096);
    int j = i4 & 7, l = (i4 >> 3) & 63, t = i4 >> 9;
    int g = l >> 4, r16 = l & 15;
    int nf = t & 3, ks = t >> 2;
    int k = 32 * ks + 8 * g + j, e = 16 * nf + r16;
    wl2f[i4] = f2bf(Wl2[e * 64 + k]);
  }
}

// ---- K_A: x -> down-proj -> LN -> SwiGLU -> a[] (bf16). 16 rows/WG, 4 waves.
__global__ __launch_bounds__(256, 6)
void k_act(const float* __restrict__ xg,
           const float* __restrict__ gamma, const float* __restrict__ beta,
           const float* __restrict__ bl1, const float* __restrict__ bl2,
           const ushort* __restrict__ wcf,
           const ushort* __restrict__ wl1f, const ushort* __restrict__ wl2f,
           ushort* __restrict__ ag) {
  __shared__ ushort smem[12416];
  ushort (*x_lds)[776] = reinterpret_cast<ushort(*)[776]>(smem);
  float  (*d_lds)[68]  = reinterpret_cast<float (*)[68]>(smem);
  ushort (*n_lds)[72]  = reinterpret_cast<ushort(*)[72]>(reinterpret_cast<char*>(smem) + 4608);

  const int tid = threadIdx.x;
  const int w = tid >> 6, l = tid & 63, g = l >> 4, r16 = l & 15;
  const int row0 = blockIdx.x * 16;

  // Phase A: stage x (16x768 f32) -> LDS bf16, float4-vectorized, coalesced.
  #pragma unroll
  for (int i = 0; i < 12; ++i) {
    int f4 = i * 256 + tid;                    // 0..3071
    int r = f4 / 192;                          // 768/4=192 float4 per row
    int c4 = (f4 - r * 192) * 4;
    const float4 v = *reinterpret_cast<const float4*>(xg + (size_t)(row0 + r) * CDIM + c4);
    ushort4 b;
    b.x = f2bf(v.x); b.y = f2bf(v.y); b.z = f2bf(v.z); b.w = f2bf(v.w);
    *reinterpret_cast<ushort4*>(&x_lds[r][c4]) = b;
  }
  __syncthreads();

  // Phase B: d(16x64) = x(16x768) * Wcomb^T. Wave w owns n-frag w.
  f32x4 dacc = {0.f, 0.f, 0.f, 0.f};
  #pragma unroll 8
  for (int ks = 0; ks < 24; ++ks) {
    bf16x8 a = *reinterpret_cast<const bf16x8*>(&x_lds[r16][ks * 32 + 8 * g]);
    bf16x8 b = *reinterpret_cast<const bf16x8*>(wcf + ((size_t)(ks * 4 + w) * 64 + l) * 8);
    dacc = __builtin_amdgcn_mfma_f32_16x16x32_bf16(a, b, dacc, 0, 0, 0);
  }
  __syncthreads();                             // all x reads done before d overwrite
  #pragma unroll
  for (int rg = 0; rg < 4; ++rg) d_lds[4 * g + rg][16 * w + r16] = dacc[rg];
  __syncthreads();

  // Phase C: LayerNorm over D=64.
  {
    int row = 4 * w + g;
    f32x4 v = *reinterpret_cast<const f32x4*>(&d_lds[row][4 * r16]);
    float s  = v[0] + v[1] + v[2] + v[3];
    float sq = v[0]*v[0] + v[1]*v[1] + v[2]*v[2] + v[3]*v[3];
    #pragma unroll
    for (int m = 1; m < 16; m <<= 1) {
      s  += __shfl_xor(s, m, 64);
      sq += __shfl_xor(sq, m, 64);
    }
    float mu  = s * (1.f / 64.f);
    float var = sq * (1.f / 64.f) - mu * mu;
    float rs  = rsqrtf(var + 1e-5f);
    const float4 gm = *reinterpret_cast<const float4*>(gamma + 4 * r16);
    const float4 bt = *reinterpret_cast<const float4*>(beta  + 4 * r16);
    ushort4 nb;
    nb.x = f2bf((v[0] - mu) * rs * gm.x + bt.x);
    nb.y = f2bf((v[1] - mu) * rs * gm.y + bt.y);
    nb.z = f2bf((v[2] - mu) * rs * gm.z + bt.z);
    nb.w = f2bf((v[3] - mu) * rs * gm.w + bt.w);
    *reinterpret_cast<ushort4*>(&n_lds[row][4 * r16]) = nb;
  }
  __syncthreads();

  // Phase D: o1/o2 (16x64, K=64) + bias + swish*gate -> global a[] (bf16).
  {
    bf16x8 a0 = *reinterpret_cast<const bf16x8*>(&n_lds[r16][8 * g]);
    bf16x8 a1 = *reinterpret_cast<const bf16x8*>(&n_lds[r16][32 + 8 * g]);
    bf16x8 b10 = *reinterpret_cast<const bf16x8*>(wl1f + ((size_t)(0 * 4 + w) * 64 + l) * 8);
    bf16x8 b11 = *reinterpret_cast<const bf16x8*>(wl1f + ((size_t)(1 * 4 + w) * 64 + l) * 8);
    bf16x8 b20 = *reinterpret_cast<const bf16x8*>(wl2f + ((size_t)(0 * 4 + w) * 64 + l) * 8);
    bf16x8 b21 = *reinterpret_cast<const bf16x8*>(wl2f + ((size_t)(1 * 4 + w) * 64 + l) * 8);
    f32x4 z = {0.f, 0.f, 0.f, 0.f};
    f32x4 acc1 = __builtin_amdgcn_mfma_f32_16x16x32_bf16(a0, b10, z, 0, 0, 0);
    acc1 = __builtin_amdgcn_mfma_f32_16x16x32_bf16(a1, b11, acc1, 0, 0, 0);
    f32x4 acc2 = __builtin_amdgcn_mfma_f32_16x16x32_bf16(a0, b20, z, 0, 0, 0);
    acc2 = __builtin_amdgcn_mfma_f32_16x16x32_bf16(a1, b21, acc2, 0, 0, 0);
    float bv1 = bl1[16 * w + r16];
    float bv2 = bl2[16 * w + r16];
    #pragma unroll
    for (int rg = 0; rg < 4; ++rg) {
      float o1 = acc1[rg] + bv1;
      float o2 = acc2[rg] + bv2;
      float sw = o1 / (1.f + __expf(-o1));       // o1*sigmoid(o1)
      ag[(size_t)(row0 + 4 * g + rg) * 64 + 16 * w + r16] = f2bf(sw * o2);
    }
  }
}

// ---- K_B: out = res + a * Wup^T.  Register-streamed res.
// 2048 blocks x 256 thr (4 waves). Lane l (wave w): out-row row0+(l&15),
// out-cols 256w + 16*nfl + 4*(l>>4) + {0..3}, nfl=0..15.
// All 16 res float4 loads issued upfront from ONE base (imm offsets 64*nfl);
// wupf (L2-resident) loaded per-nfl AFTER res (in-order retirement never
// makes MFMA wait on the res stream).
__global__ __launch_bounds__(256, 3)
void k_up(const ushort* __restrict__ ag, const float* __restrict__ resg,
          const ushort* __restrict__ wupf, float* __restrict__ outg) {
  __shared__ ushort a_lds[16][68];
  const int tid = threadIdx.x;
  const int w = tid >> 6, l = tid & 63, g = l >> 4, r16 = l & 15;
  const int row0 = blockIdx.x * 16;

  // stage a-tile (16x64 bf16 = 2KB), coalesced ushort4
  {
    int e = tid * 4;                 // 0..1023
    int r = e >> 6, c = e & 63;
    ushort4 v = *reinterpret_cast<const ushort4*>(ag + (size_t)(row0 + r) * 64 + c);
    *reinterpret_cast<ushort4*>(&a_lds[r][c]) = v;
  }

  const float* rbase = resg + (size_t)(row0 + r16) * QDIM + 256 * w + 4 * g;
  float*       obase = outg + (size_t)(row0 + r16) * QDIM + 256 * w + 4 * g;

  // All res loads in flight before anything else touches vmcnt.
  float4 rv[16];
  #pragma unroll
  for (int nfl = 0; nfl < 16; ++nfl)
    rv[nfl] = *reinterpret_cast<const float4*>(rbase + 16 * nfl);
  __builtin_amdgcn_sched_barrier(0);   // keep wupf loads/MFMA after res issue

  __syncthreads();
  const bf16x8 af0 = *reinterpret_cast<const bf16x8*>(&a_lds[r16][8 * g]);        // k 0..31
  const bf16x8 af1 = *reinterpret_cast<const bf16x8*>(&a_lds[r16][32 + 8 * g]);   // k 32..63

  #pragma unroll
  for (int nfl = 0; nfl < 16; ++nfl) {
    size_t nf = 16 * w + nfl;
    bf16x8 b0 = *reinterpret_cast<const bf16x8*>(wupf + ((nf * 2 + 0) * 64 + l) * 8);
    bf16x8 b1 = *reinterpret_cast<const bf16x8*>(wupf + ((nf * 2 + 1) * 64 + l) * 8);
    f32x4 t = {0.f, 0.f, 0.f, 0.f};
    t = __builtin_amdgcn_mfma_f32_16x16x32_bf16(b0, af0, t, 0, 0, 0);
    t = __builtin_amdgcn_mfma_f32_16x16x32_bf16(b1, af1, t, 0, 0, 0);
    float4 o;
    o.x = rv[nfl].x + t[0]; o.y = rv[nfl].y + t[1];
    o.z = rv[nfl].z + t[2]; o.w = rv[nfl].w + t[3];
    *reinterpret_cast<float4*>(obase + 16 * nfl) = o;
  }
}

extern "C" void kernel_launch(void* const* d_in, const int* in_sizes, int n_in,
                              void* d_out, int out_size, void* d_ws, size_t ws_size,
                              hipStream_t stream) {
  (void)in_sizes; (void)n_in; (void)out_size; (void)ws_size;
  const float* x     = (const float*)d_in[0];
  const float* resid = (const float*)d_in[1];
  const float* Wproj = (const float*)d_in[2];
  const float* Wdown = (const float*)d_in[3];
  const float* gamma = (const float*)d_in[4];
  const float* beta  = (const float*)d_in[5];
  const float* Wl1   = (const float*)d_in[6];
  const float* bl1   = (const float*)d_in[7];
  const float* Wl2   = (const float*)d_in[8];
  const float* bl2   = (const float*)d_in[9];
  const float* Wup   = (const float*)d_in[10];
  float* out = (float*)d_out;

  char* ws = (char*)d_ws;
  float*  part = (float*)(ws);                   // 8*768*64*4 = 1,572,864 B
  ushort* wcf  = (ushort*)(ws + 1572864);        // 49152*2 =  98,304 B
  ushort* wupf = (ushort*)(ws + 1671168);        // 65536*2 = 131,072 B
  ushort* wl1f = (ushort*)(ws + 1802240);        //  4096*2 =   8,192 B
  ushort* wl2f = (ushort*)(ws + 1810432);        //  4096*2 =   8,192 B
  ushort* ag   = (ushort*)(ws + 1818624);        // 32768*64*2 = 4,194,304 B (end ~6.0MB)

  k_wcomb  <<<768, 64, 0, stream>>>(Wproj, Wdown, part);
  k_arrange<<<480, 256, 0, stream>>>(part, Wup, Wl1, Wl2, wcf, wupf, wl1f, wl2f);
  k_act    <<<2048, 256, 0, stream>>>(x, gamma, beta, bl1, bl2, wcf, wl1f, wl2f, ag);
  k_up     <<<2048, 256, 0, stream>>>(ag, resid, wupf, out);
}

// Round 7
// 121.038 us; speedup vs baseline: 1.0935x; 1.0518x over previous
//
#include <hip/hip_runtime.h>

// BottleneckAdapter: out = residual + Wup·( swish(Wl1·n+bl1) * (Wl2·n+bl2) ),
// n = LN( (Wdown·Wproj)·x ).  W_comb = Wdown@Wproj precomputed per-launch.
//
// Dims: B=16 S=2048 C=768 Q=1024 D=64 -> ROWS=32768.
// R7: single fused main kernel. res loads issued after x staging, PINNED in
//     VGPRs via asm (defeats load sinking — R6's failure, VGPR=60 proved the
//     compiler sank them), consumed only in phase E. Latency window = whole
//     B/C/D compute span. No ag round-trip, one launch fewer.

#define CDIM 768
#define QDIM 1024

typedef __attribute__((ext_vector_type(8))) short bf16x8;
typedef __attribute__((ext_vector_type(4))) float f32x4;

__device__ __forceinline__ ushort f2bf(float f) {
  union { float f; unsigned u; } v; v.f = f;
  unsigned r = v.u + 0x7fffu + ((v.u >> 16) & 1u);   // RNE
  return (ushort)(r >> 16);
}

// ---- K1: partial W_comb[d][c] = sum_q Wdown[d][q]*Wproj[q][c], split in 8 q-chunks.
// part[qc][c][d]  (8 x 768 x 64 f32)
__global__ void k_wcomb(const float* __restrict__ Wproj, const float* __restrict__ Wdown,
                        float* __restrict__ part) {
  int bid = blockIdx.x;                 // 768 blocks = 12 cb * 8 db * 8 qc
  int cb = bid % 12, db = (bid / 12) % 8, qc = bid / 96;
  int l = threadIdx.x;                  // 64
  int c = cb * 64 + l;
  float acc[8];
  #pragma unroll
  for (int i = 0; i < 8; ++i) acc[i] = 0.f;
  int q0 = qc * 128;
  for (int q = q0; q < q0 + 128; ++q) {
    float xp = Wproj[q * CDIM + c];     // coalesced across lanes
    #pragma unroll
    for (int i = 0; i < 8; ++i)
      acc[i] = fmaf(Wdown[(db * 8 + i) * QDIM + q], xp, acc[i]);  // uniform, L2
  }
  #pragma unroll
  for (int i = 0; i < 8; ++i)
    part[((size_t)qc * CDIM + c) * 64 + db * 8 + i] = acc[i];
}

// ---- K2: sum partials + arrange all weights into MFMA fragment order (bf16).
// Fragment convention (k-permutation trick; cancels between the two operands):
// element (lane l, j) of tile (ks,nf) = M[16*nf+(l&15)][32*ks + 8*(l>>4)+j]
__global__ void k_arrange(const float* __restrict__ part, const float* __restrict__ Wup,
                          const float* __restrict__ Wl1, const float* __restrict__ Wl2,
                          ushort* __restrict__ wcf, ushort* __restrict__ wupf,
                          ushort* __restrict__ wl1f, ushort* __restrict__ wl2f) {
  int idx = blockIdx.x * 256 + threadIdx.x;      // 480*256 = 122880 exactly
  if (idx < 49152) {                             // wcf: flat = ((ks*4+nf)*64+l)*8+j, ks<24
    int i0 = idx;
    int j = i0 & 7, l = (i0 >> 3) & 63, t = i0 >> 9;
    int g = l >> 4, r16 = l & 15;
    int nf = t & 3, ks = t >> 2;
    int k = 32 * ks + 8 * g + j, n = 16 * nf + r16;   // k=c-index, n=d-index
    float s = 0.f;
    #pragma unroll
    for (int qc = 0; qc < 8; ++qc) s += part[((size_t)qc * CDIM + k) * 64 + n];
    wcf[i0] = f2bf(s);
  } else if (idx < 49152 + 65536) {              // wupf: flat = ((nf*2+ks)*64+l)*8+j, nf<64
    int i2 = idx - 49152;
    int j = i2 & 7, l = (i2 >> 3) & 63, t = i2 >> 9;
    int g = l >> 4, r16 = l & 15;
    int ks = t & 1, nf = t >> 1;
    int k = 32 * ks + 8 * g + j, n = 16 * nf + r16;   // Wup row n, k-col
    wupf[i2] = f2bf(Wup[n * 64 + k]);
  } else if (idx < 49152 + 65536 + 4096) {       // wl1f: flat = ((ks*4+nf)*64+l)*8+j
    int i3 = idx - (49152 + 65536);
    int j = i3 & 7, l = (i3 >> 3) & 63, t = i3 >> 9;
    int g = l >> 4, r16 = l & 15;
    int nf = t & 3, ks = t >> 2;
    int k = 32 * ks + 8 * g + j, e = 16 * nf + r16;   // o1[e] = sum_k n[k]*Wl1[e][k]
    wl1f[i3] = f2bf(Wl1[e * 64 + k]);
  } else {                                       // wl2f
    int i4 = idx - (49152 + 65536 + 4096);
    int j = i4 & 7, l = (i4 >> 3) & 63, t = i4 >> 9;
    int g = l >> 4, r16 = l & 15;
    int nf = t & 3, ks = t >> 2;
    int k = 32 * ks + 8 * g + j, e = 16 * nf + r16;
    wl2f[i4] = f2bf(Wl2[e * 64 + k]);
  }
}

// ---- K_MAIN: fully fused. 16 rows/WG, 4 waves, 3 blocks/CU.
__global__ __launch_bounds__(256, 3)
void k_main(const float* __restrict__ xg, const float* __restrict__ resg,
            const float* __restrict__ gamma, const float* __restrict__ beta,
            const float* __restrict__ bl1, const float* __restrict__ bl2,
            const ushort* __restrict__ wcf, const ushort* __restrict__ wupf,
            const ushort* __restrict__ wl1f, const ushort* __restrict__ wl2f,
            float* __restrict__ outg) {
  // Union region, 24832 B:
  //   phase A/B : x_lds [16][776] ushort (full region)
  //   phase B->C: d_lds [16][68]  float  (byte 0;    x dead after barrier)
  //   phase C->D: n_lds [16][72]  ushort (byte 4608)
  //   phase D->E: a_lds [16][72]  ushort (byte 8192)
  __shared__ ushort smem[12416];
  ushort (*x_lds)[776] = reinterpret_cast<ushort(*)[776]>(smem);
  float  (*d_lds)[68]  = reinterpret_cast<float (*)[68]>(smem);
  ushort (*n_lds)[72]  = reinterpret_cast<ushort(*)[72]>(reinterpret_cast<char*>(smem) + 4608);
  ushort (*a_lds)[72]  = reinterpret_cast<ushort(*)[72]>(reinterpret_cast<char*>(smem) + 8192);

  const int tid = threadIdx.x;
  const int w = tid >> 6, l = tid & 63, g = l >> 4, r16 = l & 15;
  const int row0 = blockIdx.x * 16;

  // Phase A: stage x (16x768 f32) -> LDS bf16, float4-vectorized, coalesced.
  float4 xv[12];
  #pragma unroll
  for (int i = 0; i < 12; ++i) {
    int f4 = i * 256 + tid;                    // 0..3071
    int r = f4 / 192;                          // 768/4=192 float4 per row
    int c4 = (f4 - r * 192) * 4;
    xv[i] = *reinterpret_cast<const float4*>(xg + (size_t)(row0 + r) * CDIM + c4);
  }
  #pragma unroll
  for (int i = 0; i < 12; ++i) {
    int f4 = i * 256 + tid;
    int r = f4 / 192;
    int c4 = (f4 - r * 192) * 4;
    ushort4 b;
    b.x = f2bf(xv[i].x); b.y = f2bf(xv[i].y); b.z = f2bf(xv[i].z); b.w = f2bf(xv[i].w);
    *reinterpret_cast<ushort4*>(&x_lds[r][c4]) = b;
  }

  // res loads for phase E: issue NOW, pin in VGPRs, consume after B/C/D.
  // Lane mapping matches phase E: row r16, cols 256w+16nfl+4g+{0..3}.
  const float* rbase = resg + (size_t)(row0 + r16) * QDIM + 256 * w + 4 * g;
  f32x4 rv[16];
  #pragma unroll
  for (int nfl = 0; nfl < 16; ++nfl)
    rv[nfl] = *reinterpret_cast<const f32x4*>(rbase + 16 * nfl);
  #pragma unroll
  for (int nfl = 0; nfl < 16; ++nfl)
    asm volatile("" : "+v"(rv[nfl]));          // force materialization (anti-sink)
  __builtin_amdgcn_sched_barrier(0);

  __syncthreads();

  // Phase B: d(16x64) = x(16x768) * Wcomb^T. Wave w owns n-frag w.
  f32x4 dacc = {0.f, 0.f, 0.f, 0.f};
  #pragma unroll 4
  for (int ks = 0; ks < 24; ++ks) {
    bf16x8 a = *reinterpret_cast<const bf16x8*>(&x_lds[r16][ks * 32 + 8 * g]);
    bf16x8 b = *reinterpret_cast<const bf16x8*>(wcf + ((size_t)(ks * 4 + w) * 64 + l) * 8);
    dacc = __builtin_amdgcn_mfma_f32_16x16x32_bf16(a, b, dacc, 0, 0, 0);
  }
  __syncthreads();                             // all x reads done before d overwrite
  #pragma unroll
  for (int rg = 0; rg < 4; ++rg) d_lds[4 * g + rg][16 * w + r16] = dacc[rg];
  __syncthreads();

  // Phase C: LayerNorm over D=64. Wave w rows 4w..4w+3.
  {
    int row = 4 * w + g;
    f32x4 v = *reinterpret_cast<const f32x4*>(&d_lds[row][4 * r16]);
    float s  = v[0] + v[1] + v[2] + v[3];
    float sq = v[0]*v[0] + v[1]*v[1] + v[2]*v[2] + v[3]*v[3];
    #pragma unroll
    for (int m = 1; m < 16; m <<= 1) {
      s  += __shfl_xor(s, m, 64);
      sq += __shfl_xor(sq, m, 64);
    }
    float mu  = s * (1.f / 64.f);
    float var = sq * (1.f / 64.f) - mu * mu;
    float rs  = rsqrtf(var + 1e-5f);
    const float4 gm = *reinterpret_cast<const float4*>(gamma + 4 * r16);
    const float4 bt = *reinterpret_cast<const float4*>(beta  + 4 * r16);
    ushort4 nb;
    nb.x = f2bf((v[0] - mu) * rs * gm.x + bt.x);
    nb.y = f2bf((v[1] - mu) * rs * gm.y + bt.y);
    nb.z = f2bf((v[2] - mu) * rs * gm.z + bt.z);
    nb.w = f2bf((v[3] - mu) * rs * gm.w + bt.w);
    *reinterpret_cast<ushort4*>(&n_lds[row][4 * r16]) = nb;
  }
  __syncthreads();

  // Phase D: o1/o2 (16x64, K=64) + bias + swish*gate -> a_lds.
  {
    bf16x8 a0 = *reinterpret_cast<const bf16x8*>(&n_lds[r16][8 * g]);
    bf16x8 a1 = *reinterpret_cast<const bf16x8*>(&n_lds[r16][32 + 8 * g]);
    bf16x8 b10 = *reinterpret_cast<const bf16x8*>(wl1f + ((size_t)(0 * 4 + w) * 64 + l) * 8);
    bf16x8 b11 = *reinterpret_cast<const bf16x8*>(wl1f + ((size_t)(1 * 4 + w) * 64 + l) * 8);
    bf16x8 b20 = *reinterpret_cast<const bf16x8*>(wl2f + ((size_t)(0 * 4 + w) * 64 + l) * 8);
    bf16x8 b21 = *reinterpret_cast<const bf16x8*>(wl2f + ((size_t)(1 * 4 + w) * 64 + l) * 8);
    f32x4 z = {0.f, 0.f, 0.f, 0.f};
    f32x4 acc1 = __builtin_amdgcn_mfma_f32_16x16x32_bf16(a0, b10, z, 0, 0, 0);
    acc1 = __builtin_amdgcn_mfma_f32_16x16x32_bf16(a1, b11, acc1, 0, 0, 0);
    f32x4 acc2 = __builtin_amdgcn_mfma_f32_16x16x32_bf16(a0, b20, z, 0, 0, 0);
    acc2 = __builtin_amdgcn_mfma_f32_16x16x32_bf16(a1, b21, acc2, 0, 0, 0);
    float bv1 = bl1[16 * w + r16];
    float bv2 = bl2[16 * w + r16];
    #pragma unroll
    for (int rg = 0; rg < 4; ++rg) {
      float o1 = acc1[rg] + bv1;
      float o2 = acc2[rg] + bv2;
      float sw = o1 / (1.f + __expf(-o1));       // o1*sigmoid(o1)
      a_lds[4 * g + rg][16 * w + r16] = f2bf(sw * o2);
    }
  }
  __syncthreads();

  // Phase E: up(16x1024, K=64) + residual add, rv already resident.
  // Swapped operands: lane l -> out-row r16, out-cols 256w+16nfl+4g+{0..3}.
  {
    const bf16x8 af0 = *reinterpret_cast<const bf16x8*>(&a_lds[r16][8 * g]);
    const bf16x8 af1 = *reinterpret_cast<const bf16x8*>(&a_lds[r16][32 + 8 * g]);
    float* obase = outg + (size_t)(row0 + r16) * QDIM + 256 * w + 4 * g;
    #pragma unroll
    for (int nfl = 0; nfl < 16; ++nfl) {
      size_t nf = 16 * w + nfl;
      bf16x8 b0 = *reinterpret_cast<const bf16x8*>(wupf + ((nf * 2 + 0) * 64 + l) * 8);
      bf16x8 b1 = *reinterpret_cast<const bf16x8*>(wupf + ((nf * 2 + 1) * 64 + l) * 8);
      f32x4 t = {0.f, 0.f, 0.f, 0.f};
      t = __builtin_amdgcn_mfma_f32_16x16x32_bf16(b0, af0, t, 0, 0, 0);
      t = __builtin_amdgcn_mfma_f32_16x16x32_bf16(b1, af1, t, 0, 0, 0);
      f32x4 o = rv[nfl] + t;
      *reinterpret_cast<f32x4*>(obase + 16 * nfl) = o;
    }
  }
}

extern "C" void kernel_launch(void* const* d_in, const int* in_sizes, int n_in,
                              void* d_out, int out_size, void* d_ws, size_t ws_size,
                              hipStream_t stream) {
  (void)in_sizes; (void)n_in; (void)out_size; (void)ws_size;
  const float* x     = (const float*)d_in[0];
  const float* resid = (const float*)d_in[1];
  const float* Wproj = (const float*)d_in[2];
  const float* Wdown = (const float*)d_in[3];
  const float* gamma = (const float*)d_in[4];
  const float* beta  = (const float*)d_in[5];
  const float* Wl1   = (const float*)d_in[6];
  const float* bl1   = (const float*)d_in[7];
  const float* Wl2   = (const float*)d_in[8];
  const float* bl2   = (const float*)d_in[9];
  const float* Wup   = (const float*)d_in[10];
  float* out = (float*)d_out;

  char* ws = (char*)d_ws;
  float*  part = (float*)(ws);                   // 8*768*64*4 = 1,572,864 B
  ushort* wcf  = (ushort*)(ws + 1572864);        // 49152*2 =  98,304 B
  ushort* wupf = (ushort*)(ws + 1671168);        // 65536*2 = 131,072 B
  ushort* wl1f = (ushort*)(ws + 1802240);        //  4096*2 =   8,192 B
  ushort* wl2f = (ushort*)(ws + 1810432);        //  4096*2 =   8,192 B

  k_wcomb  <<<768, 64, 0, stream>>>(Wproj, Wdown, part);
  k_arrange<<<480, 256, 0, stream>>>(part, Wup, Wl1, Wl2, wcf, wupf, wl1f, wl2f);
  k_main   <<<2048, 256, 0, stream>>>(x, resid, gamma, beta, bl1, bl2,
                                      wcf, wupf, wl1f, wl2f, out);
}